// Round 10
// baseline (121.845 us; speedup 1.0000x reference)
//
#include <hip/hip_runtime.h>
#include <hip/hip_bf16.h>
#include <stdint.h>

// SimCLR loss, B=4096, D=256, T=0.1.
// loss = (1/2B) * sum_i [ log(sum_{j!=i} exp(sim_ij)) - sim_{i,pair(i)} ]
// sim in [-10,10] => no max-subtraction needed.
// R10: R9 + __launch_bounds__(256,1). R9's VGPR_Count=84 proved the
// compiler sank fragment loads next to their MFMAs (needs ~200 regs to
// keep afr+bfr+acc resident) -> ~16 exposed L2 latencies per block.
// With 1 block/CU the allocator can hold everything: one load burst,
// one vmcnt drain, then 32 uninterrupted MFMAs/wave. Kernel is
// intra-block latency-bound, not occupancy-bound, so 4 waves/CU is fine.
// Zero atomics (conflict-free row/col partial arrays, R9), direct-from-L2
// gathers (no LDS/barriers), MX-scaled fp8 MFMA 16x16x128 (scales=1.0),
// lower-triangle tiles with symmetric row+col contributions.

#define BROWS 4096
#define NROWS 8192
#define DDIM  256
#define TINV  10.0f
#define LOG2E10 14.4269504088896340736f   // 10 * log2(e)
#define EPSN  1e-8f

#define TM    128
#define NTILE (NROWS / TM)               // 64
#define NTRI  (NTILE * (NTILE + 1) / 2)  // 2080
#define NSLOT 128                        // 64 tiles * 2 waves

typedef float f32x4 __attribute__((ext_vector_type(4)));
typedef int   i32x8 __attribute__((ext_vector_type(8)));

// ------- prep: norms + fp8 unit rows + pos + zero partials ----------------
__global__ __launch_bounds__(256) void prep_kernel(
    const float* __restrict__ z1, const float* __restrict__ z2,
    unsigned int* __restrict__ zn8, float* __restrict__ pos,
    float* __restrict__ parts, float* __restrict__ out) {
  int t = threadIdx.x;
  int i    = blockIdx.x * 4 + (t >> 6);
  int lane = t & 63;
  // zero rowpart+colpart: 2 * 128 * 8192 f32 = 8 MB; 1024 blocks * 8 KB
  {
    float4* pz = (float4*)(parts + (size_t)blockIdx.x * 2048);
    ((float4*)pz)[t]       = make_float4(0.f, 0.f, 0.f, 0.f);
    ((float4*)pz)[t + 256] = make_float4(0.f, 0.f, 0.f, 0.f);
  }
  if (blockIdx.x == 0 && t == 0) out[0] = 0.f;

  float4 a = ((const float4*)(z1 + (size_t)i * DDIM))[lane];
  float4 b = ((const float4*)(z2 + (size_t)i * DDIM))[lane];
  float s1 = a.x*a.x + a.y*a.y + a.z*a.z + a.w*a.w;
  float s2 = b.x*b.x + b.y*b.y + b.z*b.z + b.w*b.w;
  float dt = a.x*b.x + a.y*b.y + a.z*b.z + a.w*b.w;
  #pragma unroll
  for (int off = 32; off; off >>= 1) {
    s1 += __shfl_xor(s1, off, 64);
    s2 += __shfl_xor(s2, off, 64);
    dt += __shfl_xor(dt, off, 64);
  }
  float i1 = 1.0f / fmaxf(sqrtf(s1), EPSN);
  float i2 = 1.0f / fmaxf(sqrtf(s2), EPSN);
  if (lane == 0) pos[i] = dt * i1 * i2 * TINV;
  int p1 = __builtin_amdgcn_cvt_pk_fp8_f32(a.x*i1, a.y*i1, 0, false);
  p1     = __builtin_amdgcn_cvt_pk_fp8_f32(a.z*i1, a.w*i1, p1, true);
  int p2 = __builtin_amdgcn_cvt_pk_fp8_f32(b.x*i2, b.y*i2, 0, false);
  p2     = __builtin_amdgcn_cvt_pk_fp8_f32(b.z*i2, b.w*i2, p2, true);
  zn8[(size_t)i * 64 + lane]           = (unsigned int)p1;
  zn8[(size_t)(i + BROWS) * 64 + lane] = (unsigned int)p2;
}

__device__ __forceinline__ void decode_tri(int tid, int& bi, int& bj) {
  int x = (int)((sqrtf(8.0f * tid + 1.0f) - 1.0f) * 0.5f);
  while ((x + 1) * (x + 2) / 2 <= tid) ++x;
  while (x * (x + 1) / 2 > tid) --x;
  bi = x; bj = tid - x * (x + 1) / 2;
}

// ---------------- direct-from-L2 Gram tile + exp + partial sums ------------
__global__ __launch_bounds__(256, 1) void simexp_kernel(
    const unsigned char* __restrict__ zn8,
    float* __restrict__ rowpart, float* __restrict__ colpart) {
  int bi, bj;
  decode_tri(blockIdx.x, bi, bj);

  const int t = threadIdx.x;
  const int wave = t >> 6, lane = t & 63;
  const int wr = wave >> 1, wc = wave & 1;
  const int quad = lane >> 4, l15 = lane & 15;
  const int rowA0 = bi * TM, rowB0 = bj * TM;

  const unsigned char* Abase =
      zn8 + (size_t)(rowA0 + wr * 64 + l15) * 256 + quad * 32;
  const unsigned char* Bbase =
      zn8 + (size_t)(rowB0 + wc * 64 + l15) * 256 + quad * 32;

  // load burst: all fragments resident (launch_bounds(256,1) -> ~256 VGPRs)
  i32x8 afr[4][2], bfr[4][2];
  #pragma unroll
  for (int mi = 0; mi < 4; ++mi)
    #pragma unroll
    for (int kb = 0; kb < 2; ++kb) {
      afr[mi][kb] = *(const i32x8*)(Abase + (size_t)mi * 16 * 256 + kb * 128);
      bfr[mi][kb] = *(const i32x8*)(Bbase + (size_t)mi * 16 * 256 + kb * 128);
    }

  f32x4 acc[4][4] = {};
  #pragma unroll
  for (int kb = 0; kb < 2; ++kb)
    #pragma unroll
    for (int mi = 0; mi < 4; ++mi)
      #pragma unroll
      for (int nj = 0; nj < 4; ++nj)
        acc[mi][nj] = __builtin_amdgcn_mfma_scale_f32_16x16x128_f8f6f4(
            afr[mi][kb], bfr[nj][kb], acc[mi][nj],
            0, 0,                       // cbsz=fp8(e4m3), blgp=fp8(e4m3)
            0, 0x7F7F7F7F,              // scale_a = 1.0
            0, 0x7F7F7F7F);             // scale_b = 1.0

  // ---- epilogue: exp (diag masked), row + col partial sums (NO atomics) --
  float cs[4] = {0.f, 0.f, 0.f, 0.f};
  float* rp = rowpart + (size_t)(bj * 2 + wc) * NROWS;   // unique (slot,row)
  #pragma unroll
  for (int mi = 0; mi < 4; ++mi) {
    float rs[4] = {0.f, 0.f, 0.f, 0.f};
    if (bi == bj) {
      #pragma unroll
      for (int nj = 0; nj < 4; ++nj) {
        int gj = wc * 64 + nj * 16 + l15;              // tile-local col
        #pragma unroll
        for (int r = 0; r < 4; ++r) {
          int gi = wr * 64 + mi * 16 + quad * 4 + r;   // tile-local row
          float e = (gi == gj) ? 0.f : exp2f(acc[mi][nj][r] * LOG2E10);
          rs[r] += e;
          cs[nj] += e;
        }
      }
    } else {
      #pragma unroll
      for (int nj = 0; nj < 4; ++nj)
        #pragma unroll
        for (int r = 0; r < 4; ++r) {
          float e = exp2f(acc[mi][nj][r] * LOG2E10);
          rs[r] += e;
          cs[nj] += e;
        }
    }
    #pragma unroll
    for (int r = 0; r < 4; ++r) {
      float v = rs[r];
      v += __shfl_xor(v, 1, 64);
      v += __shfl_xor(v, 2, 64);
      v += __shfl_xor(v, 4, 64);
      v += __shfl_xor(v, 8, 64);
      if (l15 == 0)
        rp[rowA0 + wr * 64 + mi * 16 + quad * 4 + r] = v;
    }
  }
  if (bi != bj) {
    float* cp = colpart + (size_t)(bi * 2 + wr) * NROWS; // unique (slot,col)
    #pragma unroll
    for (int nj = 0; nj < 4; ++nj) {
      float v = cs[nj];
      v += __shfl_xor(v, 16, 64);
      v += __shfl_xor(v, 32, 64);
      if (quad == 0)
        cp[rowB0 + wc * 64 + nj * 16 + l15] = v;
    }
  }
}

// ---------------- finalize: sum 256 slots/row, log, loss -------------------
__global__ __launch_bounds__(256) void finalize_kernel(
    const float* __restrict__ rowpart, const float* __restrict__ colpart,
    const float* __restrict__ pos, float* __restrict__ out) {
  __shared__ float red[4];
  int t = threadIdx.x;
  int idx = blockIdx.x * 256 + t;
  float v = 0.f;
  #pragma unroll 4
  for (int s = 0; s < NSLOT; ++s) {
    v += rowpart[(size_t)s * NROWS + idx];
    v += colpart[(size_t)s * NROWS + idx];
  }
  float s = __logf(v);
  if (idx < BROWS) s -= 2.f * pos[idx];
  #pragma unroll
  for (int off = 32; off; off >>= 1) s += __shfl_xor(s, off, 64);
  if ((t & 63) == 0) red[t >> 6] = s;
  __syncthreads();
  if (t == 0)
    atomicAdd(out, (red[0] + red[1] + red[2] + red[3]) / (float)NROWS);
}

// ---------------- launch ----------------------------------------------------
extern "C" void kernel_launch(void* const* d_in, const int* in_sizes, int n_in,
                              void* d_out, int out_size, void* d_ws, size_t ws_size,
                              hipStream_t stream) {
  const float* z1 = (const float*)d_in[0];
  const float* z2 = (const float*)d_in[1];
  char* ws = (char*)d_ws;
  unsigned int* zn8 = (unsigned int*)ws;                   // 2 MB
  float* rowpart = (float*)(ws + (2u << 20));              // 4 MB
  float* colpart = (float*)(ws + (6u << 20));              // 4 MB
  float* pos     = (float*)(ws + (10u << 20));             // 16 KB
  float* out     = (float*)d_out;

  prep_kernel<<<BROWS / 4, 256, 0, stream>>>(z1, z2, zn8, pos, rowpart, out);
  simexp_kernel<<<NTRI, 256, 0, stream>>>((const unsigned char*)zn8,
                                          rowpart, colpart);
  finalize_kernel<<<NROWS / 256, 256, 0, stream>>>(rowpart, colpart, pos, out);
}

// Round 11
// 111.034 us; speedup vs baseline: 1.0974x; 1.0974x over previous
//
#include <hip/hip_runtime.h>
#include <hip/hip_bf16.h>
#include <stdint.h>

// SimCLR loss, B=4096, D=256, T=0.1.
// loss = (1/2B) * sum_i [ log(sum_{j!=i} exp(sim_ij)) - sim_{i,pair(i)} ]
// sim in [-10,10] => no max-subtraction needed.
// R11: one WAVE = one 64x64 tile. 8256 independent 64-thread blocks, no
// barriers, no LDS. R9/R10 showed the compiler always sinks fragment loads
// into the MFMA chain (VGPR 84/92) -> serial L2 latency; instead of forcing
// ILP, this buys TLP: 8-20 resident waves/CU hide each other's stalls
// (MFMA/VALU/TA pipes co-schedule across waves). Zero atomics: conflict-free
// row/col partial slots (rowpart[bj][row], colpart[bi][col], unique writer).
// Direct-from-L2 gathers, MX-scaled fp8 MFMA 16x16x128 (scales=1.0),
// lower-triangle tiles with symmetric row+col contributions.

#define BROWS 4096
#define NROWS 8192
#define DDIM  256
#define TINV  10.0f
#define LOG2E10 14.4269504088896340736f   // 10 * log2(e)
#define EPSN  1e-8f

#define TM    64
#define NTILE (NROWS / TM)               // 128
#define NTRI  (NTILE * (NTILE + 1) / 2)  // 8256
#define NSLOT NTILE                      // 128 slots per partial array

typedef float f32x4 __attribute__((ext_vector_type(4)));
typedef int   i32x8 __attribute__((ext_vector_type(8)));

// ------- prep: norms + fp8 unit rows + pos + zero partials ----------------
__global__ __launch_bounds__(256) void prep_kernel(
    const float* __restrict__ z1, const float* __restrict__ z2,
    unsigned int* __restrict__ zn8, float* __restrict__ pos,
    float* __restrict__ parts, float* __restrict__ out) {
  int t = threadIdx.x;
  int i    = blockIdx.x * 4 + (t >> 6);
  int lane = t & 63;
  // zero rowpart+colpart: 2 * 128 * 8192 f32 = 8 MB; 1024 blocks * 8 KB
  {
    float4* pz = (float4*)(parts + (size_t)blockIdx.x * 2048);
    pz[t]       = make_float4(0.f, 0.f, 0.f, 0.f);
    pz[t + 256] = make_float4(0.f, 0.f, 0.f, 0.f);
  }
  if (blockIdx.x == 0 && t == 0) out[0] = 0.f;

  float4 a = ((const float4*)(z1 + (size_t)i * DDIM))[lane];
  float4 b = ((const float4*)(z2 + (size_t)i * DDIM))[lane];
  float s1 = a.x*a.x + a.y*a.y + a.z*a.z + a.w*a.w;
  float s2 = b.x*b.x + b.y*b.y + b.z*b.z + b.w*b.w;
  float dt = a.x*b.x + a.y*b.y + a.z*b.z + a.w*b.w;
  #pragma unroll
  for (int off = 32; off; off >>= 1) {
    s1 += __shfl_xor(s1, off, 64);
    s2 += __shfl_xor(s2, off, 64);
    dt += __shfl_xor(dt, off, 64);
  }
  float i1 = 1.0f / fmaxf(sqrtf(s1), EPSN);
  float i2 = 1.0f / fmaxf(sqrtf(s2), EPSN);
  if (lane == 0) pos[i] = dt * i1 * i2 * TINV;
  int p1 = __builtin_amdgcn_cvt_pk_fp8_f32(a.x*i1, a.y*i1, 0, false);
  p1     = __builtin_amdgcn_cvt_pk_fp8_f32(a.z*i1, a.w*i1, p1, true);
  int p2 = __builtin_amdgcn_cvt_pk_fp8_f32(b.x*i2, b.y*i2, 0, false);
  p2     = __builtin_amdgcn_cvt_pk_fp8_f32(b.z*i2, b.w*i2, p2, true);
  zn8[(size_t)i * 64 + lane]           = (unsigned int)p1;
  zn8[(size_t)(i + BROWS) * 64 + lane] = (unsigned int)p2;
}

__device__ __forceinline__ void decode_tri(int tid, int& bi, int& bj) {
  int x = (int)((sqrtf(8.0f * tid + 1.0f) - 1.0f) * 0.5f);
  while ((x + 1) * (x + 2) / 2 <= tid) ++x;
  while (x * (x + 1) / 2 > tid) --x;
  bi = x; bj = tid - x * (x + 1) / 2;
}

// ---------------- one wave = one 64x64 tile --------------------------------
__global__ __launch_bounds__(64, 2) void simexp_kernel(
    const unsigned char* __restrict__ zn8,
    float* __restrict__ rowpart, float* __restrict__ colpart) {
  int bi, bj;
  decode_tri(blockIdx.x, bi, bj);

  const int lane = threadIdx.x;          // 0..63, one wave
  const int quad = lane >> 4, l15 = lane & 15;
  const int rowA0 = bi * TM, rowB0 = bj * TM;

  const unsigned char* Abase =
      zn8 + (size_t)(rowA0 + l15) * 256 + quad * 32;
  const unsigned char* Bbase =
      zn8 + (size_t)(rowB0 + l15) * 256 + quad * 32;

  // fragments: afr[mi][kb] = 32 k-bytes [kb*128+quad*32) of row (+mi*16)
  i32x8 afr[4][2], bfr[4][2];
  #pragma unroll
  for (int mi = 0; mi < 4; ++mi)
    #pragma unroll
    for (int kb = 0; kb < 2; ++kb) {
      afr[mi][kb] = *(const i32x8*)(Abase + (size_t)mi * 16 * 256 + kb * 128);
      bfr[mi][kb] = *(const i32x8*)(Bbase + (size_t)mi * 16 * 256 + kb * 128);
    }

  f32x4 acc[4][4] = {};
  #pragma unroll
  for (int kb = 0; kb < 2; ++kb)
    #pragma unroll
    for (int mi = 0; mi < 4; ++mi)
      #pragma unroll
      for (int nj = 0; nj < 4; ++nj)
        acc[mi][nj] = __builtin_amdgcn_mfma_scale_f32_16x16x128_f8f6f4(
            afr[mi][kb], bfr[nj][kb], acc[mi][nj],
            0, 0,                       // cbsz=fp8(e4m3), blgp=fp8(e4m3)
            0, 0x7F7F7F7F,              // scale_a = 1.0
            0, 0x7F7F7F7F);             // scale_b = 1.0

  // ---- epilogue: exp (diag masked), row + col partial sums (NO atomics) --
  float cs[4] = {0.f, 0.f, 0.f, 0.f};
  float* rp = rowpart + (size_t)bj * NROWS;   // unique writer (bj, row)
  #pragma unroll
  for (int mi = 0; mi < 4; ++mi) {
    float rs[4] = {0.f, 0.f, 0.f, 0.f};
    if (bi == bj) {
      #pragma unroll
      for (int nj = 0; nj < 4; ++nj) {
        int gj = nj * 16 + l15;                  // tile-local col
        #pragma unroll
        for (int r = 0; r < 4; ++r) {
          int gi = mi * 16 + quad * 4 + r;       // tile-local row
          float e = (gi == gj) ? 0.f : exp2f(acc[mi][nj][r] * LOG2E10);
          rs[r] += e;
          cs[nj] += e;
        }
      }
    } else {
      #pragma unroll
      for (int nj = 0; nj < 4; ++nj)
        #pragma unroll
        for (int r = 0; r < 4; ++r) {
          float e = exp2f(acc[mi][nj][r] * LOG2E10);
          rs[r] += e;
          cs[nj] += e;
        }
    }
    #pragma unroll
    for (int r = 0; r < 4; ++r) {
      float v = rs[r];
      v += __shfl_xor(v, 1, 64);
      v += __shfl_xor(v, 2, 64);
      v += __shfl_xor(v, 4, 64);
      v += __shfl_xor(v, 8, 64);
      if (l15 == 0)
        rp[rowA0 + mi * 16 + quad * 4 + r] = v;
    }
  }
  if (bi != bj) {
    float* cp = colpart + (size_t)bi * NROWS;   // unique writer (bi, col)
    #pragma unroll
    for (int nj = 0; nj < 4; ++nj) {
      float v = cs[nj];
      v += __shfl_xor(v, 16, 64);
      v += __shfl_xor(v, 32, 64);
      if (quad == 0)
        cp[rowB0 + nj * 16 + l15] = v;
    }
  }
}

// ---------------- finalize: sum 256 slots/row, log, loss -------------------
__global__ __launch_bounds__(256) void finalize_kernel(
    const float* __restrict__ rowpart, const float* __restrict__ colpart,
    const float* __restrict__ pos, float* __restrict__ out) {
  __shared__ float red[4];
  int t = threadIdx.x;
  int idx = blockIdx.x * 256 + t;
  float v = 0.f;
  #pragma unroll 4
  for (int s = 0; s < NSLOT; ++s) {
    v += rowpart[(size_t)s * NROWS + idx];
    v += colpart[(size_t)s * NROWS + idx];
  }
  float s = __logf(v);
  if (idx < BROWS) s -= 2.f * pos[idx];
  #pragma unroll
  for (int off = 32; off; off >>= 1) s += __shfl_xor(s, off, 64);
  if ((t & 63) == 0) red[t >> 6] = s;
  __syncthreads();
  if (t == 0)
    atomicAdd(out, (red[0] + red[1] + red[2] + red[3]) / (float)NROWS);
}

// ---------------- launch ----------------------------------------------------
extern "C" void kernel_launch(void* const* d_in, const int* in_sizes, int n_in,
                              void* d_out, int out_size, void* d_ws, size_t ws_size,
                              hipStream_t stream) {
  const float* z1 = (const float*)d_in[0];
  const float* z2 = (const float*)d_in[1];
  char* ws = (char*)d_ws;
  unsigned int* zn8 = (unsigned int*)ws;                   // 2 MB
  float* rowpart = (float*)(ws + (2u << 20));              // 4 MB
  float* colpart = (float*)(ws + (6u << 20));              // 4 MB
  float* pos     = (float*)(ws + (10u << 20));             // 16 KB
  float* out     = (float*)d_out;

  prep_kernel<<<BROWS / 4, 256, 0, stream>>>(z1, z2, zn8, pos, rowpart, out);
  simexp_kernel<<<NTRI, 64, 0, stream>>>((const unsigned char*)zn8,
                                         rowpart, colpart);
  finalize_kernel<<<NROWS / 256, 256, 0, stream>>>(rowpart, colpart, pos, out);
}